// Round 11
// baseline (133.318 us; speedup 1.0000x reference)
//
#include <hip/hip_runtime.h>
#include <math.h>

namespace {
constexpr int S  = 2048;
constexpr int E  = 1024;
constexpr int NH = 8;
constexpr int DH = 128;
constexpr float EPSF = 1e-6f;
constexpr float INV_LN2 = 1.4426950408889634f;
}

typedef short short8 __attribute__((ext_vector_type(8)));
typedef float f32x16 __attribute__((ext_vector_type(16)));
typedef float f32x4  __attribute__((ext_vector_type(4)));

__device__ __forceinline__ unsigned short f2bf(float x) {
  unsigned int u = __float_as_uint(x);
  unsigned int r = (u + 0x7fffu + ((u >> 16) & 1u)) >> 16;   // RNE, finite inputs
  return (unsigned short)r;
}

// async 16B/lane global->LDS: LDS dest = wave-uniform base + lane*16
__device__ __forceinline__ void async_copy16(const void* g, void* l) {
  __builtin_amdgcn_global_load_lds(
      (const __attribute__((address_space(1))) unsigned int*)g,
      (__attribute__((address_space(3))) unsigned int*)l, 16, 0, 0);
}

// LPT job table: 160 jobs/head, longest-first. k(qt)=1+qt/16 parts.
__device__ const unsigned char JOB_QT[160] = {
  63,63,63,63, 62,62,62,62, 61,61,61,61, 60,60,60,60,
  59,59,59,59, 58,58,58,58, 57,57,57,57, 56,56,56,56,
  47,47,47, 46,46,46, 45,45,45, 44,44,44, 43,43,43, 42,42,42,
  31,31, 30,30, 29,29, 28,28, 15, 14,
  55,55,55,55, 54,54,54,54, 53,53,53,53, 52,52,52,52,
  51,51,51,51, 50,50,50,50, 49,49,49,49, 48,48,48,48,
  41,41,41, 40,40,40, 39,39,39, 38,38,38, 37,37,37, 36,36,36,
  27,27, 26,26, 25,25, 24,24, 13, 12,
  35,35,35, 34,34,34, 33,33,33, 32,32,32,
  23,23, 22,22, 21,21, 20,20, 11, 10,
  19,19, 18,18, 17,17, 16,16, 9, 8,
  7, 6, 5, 4, 3, 2, 1, 0
};
__device__ const unsigned char JOB_PART[160] = {
  0,1,2,3, 0,1,2,3, 0,1,2,3, 0,1,2,3,
  0,1,2,3, 0,1,2,3, 0,1,2,3, 0,1,2,3,
  0,1,2, 0,1,2, 0,1,2, 0,1,2, 0,1,2, 0,1,2,
  0,1, 0,1, 0,1, 0,1, 0, 0,
  0,1,2,3, 0,1,2,3, 0,1,2,3, 0,1,2,3,
  0,1,2,3, 0,1,2,3, 0,1,2,3, 0,1,2,3,
  0,1,2, 0,1,2, 0,1,2, 0,1,2, 0,1,2, 0,1,2,
  0,1, 0,1, 0,1, 0,1, 0, 0,
  0,1,2, 0,1,2, 0,1,2, 0,1,2,
  0,1, 0,1, 0,1, 0,1, 0, 0,
  0,1, 0,1, 0,1, 0,1, 0, 0,
  0, 0, 0, 0, 0, 0, 0, 0
};

// ---------------- kernel 1 (merged): gates GEMM + V^T + q/k cast ----------------
__global__ __launch_bounds__(256) void merged_pre_kernel(
    const float* __restrict__ q, const float* __restrict__ k, const float* __restrict__ v,
    const float* __restrict__ Wi, const float* __restrict__ Wf,
    const float* __restrict__ bi, const float* __restrict__ bfg,
    unsigned short* __restrict__ qb, unsigned short* __restrict__ kb,
    unsigned short* __restrict__ vt,
    float* __restrict__ ipre, float* __restrict__ lsf)
{
  __shared__ __align__(16) char smem[38912];
  const int b = blockIdx.x;
  const int tid = threadIdx.x;

  if (b < 128) {
    const int wv = tid >> 6, lane = tid & 63;
    const int m0 = b * 16;
    const int tr = lane & 15;
    const int ks = (lane >> 4) * 8;
    unsigned short* Wl = (unsigned short*)smem + wv * (16*264);
    float* red = (float*)(smem + 33792);
    f32x4 acc = {0.f, 0.f, 0.f, 0.f};
    const float* srcs[3] = {q, k, v};
    #pragma unroll
    for (int p = 0; p < 3; ++p) {
      const size_t wb = ((size_t)p*E + wv*256) * 8;
      #pragma unroll
      for (int it = 0; it < 8; ++it) {
        const int f = it*64 + lane;
        float4 wi4 = *reinterpret_cast<const float4*>(Wi + wb + (size_t)f*4);
        float4 wf4 = *reinterpret_cast<const float4*>(Wf + wb + (size_t)f*4);
        const int el = f >> 1, n0 = (f & 1) * 4;
        Wl[(n0+0)*264 + el] = f2bf(wi4.x);
        Wl[(n0+1)*264 + el] = f2bf(wi4.y);
        Wl[(n0+2)*264 + el] = f2bf(wi4.z);
        Wl[(n0+3)*264 + el] = f2bf(wi4.w);
        Wl[(n0+8)*264 + el] = f2bf(wf4.x);
        Wl[(n0+9)*264 + el] = f2bf(wf4.y);
        Wl[(n0+10)*264 + el] = f2bf(wf4.z);
        Wl[(n0+11)*264 + el] = f2bf(wf4.w);
      }
      const float* src = srcs[p];
      #pragma unroll
      for (int s = 0; s < 8; ++s) {
        const float* ap = src + (size_t)(m0 + tr)*E + wv*256 + s*32 + ks;
        float4 a0 = *reinterpret_cast<const float4*>(ap);
        float4 a1 = *reinterpret_cast<const float4*>(ap + 4);
        short8 af;
        af[0] = (short)f2bf(a0.x); af[1] = (short)f2bf(a0.y);
        af[2] = (short)f2bf(a0.z); af[3] = (short)f2bf(a0.w);
        af[4] = (short)f2bf(a1.x); af[5] = (short)f2bf(a1.y);
        af[6] = (short)f2bf(a1.z); af[7] = (short)f2bf(a1.w);
        short8 bf8 = *reinterpret_cast<const short8*>(&Wl[tr*264 + s*32 + ks]);
        acc = __builtin_amdgcn_mfma_f32_16x16x32_bf16(af, bf8, acc, 0, 0, 0);
      }
    }
    #pragma unroll
    for (int r = 0; r < 4; ++r)
      red[wv*256 + (lane&15)*16 + (lane>>4)*4 + r] = acc[r];
    __syncthreads();
    {
      const int n = tid & 15, m = tid >> 4;
      float val = red[0*256 + n*16 + m] + red[1*256 + n*16 + m]
                + red[2*256 + n*16 + m] + red[3*256 + n*16 + m];
      const int t = m0 + m;
      if (n < 8) {
        ipre[n*S + t] = val + bi[n];
      } else {
        float fp = val + bfg[n-8];
        lsf[(n-8)*S + t] = fminf(fp, 0.f) - log1pf(__expf(-fabsf(fp)));
      }
    }
  } else if (b < 640) {
    float (*Ts)[65] = (float(*)[65])smem;
    const int bb = b - 128;
    const int j0 = (bb & 31) * 64;
    const int d0 = ((bb >> 5) & 1) * 64;
    const int h  = bb >> 6;
    const int c = tid & 63, r4 = tid >> 6;
    #pragma unroll
    for (int rr = 0; rr < 16; ++rr) {
      int r = r4*16 + rr;
      Ts[r][c] = v[(size_t)(j0 + r)*E + h*DH + d0 + c];
    }
    __syncthreads();
    #pragma unroll
    for (int rr = 0; rr < 16; ++rr) {
      int r = r4*16 + rr;
      vt[(size_t)(h*DH + d0 + r)*S + j0 + c] = f2bf(Ts[c][r]);
    }
  } else {
    const int bb = b - 640;
    constexpr int N4 = S*E/4;
    const float4* src = (bb < 256) ? (const float4*)q : (const float4*)k;
    ushort4* dst = (bb < 256) ? (ushort4*)qb : (ushort4*)kb;
    const int b0 = (bb & 255);
    for (int i = b0*256 + tid; i < N4; i += 256*256) {
      float4 x = src[i];
      ushort4 o;
      o.x = f2bf(x.x); o.y = f2bf(x.y); o.z = f2bf(x.z); o.w = f2bf(x.w);
      dst[i] = o;
    }
  }
}

// ---------------- kernel 2: per-head scans -> a2 = a/ln2, m2 = m/ln2 ----------------
__global__ __launch_bounds__(256) void scan_kernel(
    const float* __restrict__ ipre, const float* __restrict__ lsf,
    float* __restrict__ a2_out, float* __restrict__ m2_out)
{
  const int h = blockIdx.x, tid = threadIdx.x;
  const int lane = tid & 63, wv = tid >> 6;
  constexpr int PER = S / 256;
  const int base = h*S + tid*PER;
  __shared__ float wred[4], wmax[4];

  float c[PER];
  float run = 0.f;
  #pragma unroll
  for (int u = 0; u < PER; u++) { run += lsf[base+u]; c[u] = run; }
  float s = run;
  #pragma unroll
  for (int off = 1; off < 64; off <<= 1) {
    float t = __shfl_up(s, off);
    if (lane >= off) s += t;
  }
  if (lane == 63) wred[wv] = s;
  __syncthreads();
  float wpre = 0.f;
  for (int i = 0; i < wv; i++) wpre += wred[i];
  const float excl = wpre + (s - run);

  float av[PER], mloc[PER];
  float lm = -INFINITY;
  #pragma unroll
  for (int u = 0; u < PER; u++) {
    c[u] += excl;
    av[u] = ipre[base+u] - c[u];
    lm = fmaxf(lm, av[u]);
    mloc[u] = lm;
  }
  float sm_ = lm;
  #pragma unroll
  for (int off = 1; off < 64; off <<= 1) {
    float t = __shfl_up(sm_, off);
    if (lane >= off) sm_ = fmaxf(sm_, t);
  }
  if (lane == 63) wmax[wv] = sm_;
  __syncthreads();
  float wpm = -INFINITY;
  for (int i = 0; i < wv; i++) wpm = fmaxf(wpm, wmax[i]);
  float prev = __shfl_up(sm_, 1);
  if (lane == 0) prev = -INFINITY;
  const float exclm = fmaxf(wpm, prev);
  #pragma unroll
  for (int u = 0; u < PER; u++) {
    float m = fmaxf(exclm, mloc[u]);
    a2_out[base+u] = av[u] * INV_LN2;
    m2_out[base+u] = m * INV_LN2;
  }
}

// ---------------- kernel 3: MFMA causal decay-attention, CHUNK=64, k-way split ----
// 1280 blocks: h = b&7, job = JOB_QT/JOB_PART[b>>3]; k = 1+qt/16 parts per qt.
// QK on waves 0,1 (chunk is 64 wide); PV on all 4 waves (32 d-cols each).
// k==1 (qt<16): in-kernel LN epilogue. k>=2: raw O part -> opart; combine LNs.
__global__ __launch_bounds__(256, 3) void attn_kernel(
    const unsigned short* __restrict__ qb, const unsigned short* __restrict__ kb,
    const unsigned short* __restrict__ vt,
    const float* __restrict__ a2g, const float* __restrict__ m2g,
    const float* __restrict__ ln, float* __restrict__ opart,
    float* __restrict__ out)
{
  const int h   = blockIdx.x & 7;
  const int idx = blockIdx.x >> 3;
  const int qt   = JOB_QT[idx];
  const int part = JOB_PART[idx];
  const int kparts = 1 + (qt >> 4);
  const int N = (qt + 2) >> 1;                  // ceil((qt+1)*32 / 64)
  const int jt_lo = (N * part) / kparts;
  const int jt_hi = (N * (part + 1)) / kparts;

  const int tid = threadIdx.x;
  const int w = tid >> 6, lane = tid & 63, l31 = lane & 31, half = lane >> 5;
  const int qi0 = qt * 32;

  __shared__ short Klds[64*128];    // rows j (64), 16 16B-blocks/row, blk c at pos c^(j&15)
  __shared__ short Vlds[128*64];    // rows d (128), 8 16B-blocks/row, blk c at pos c^(d&7)
  __shared__ short Psm[32*72];      // P tile 32q x 64j, stride 72 (16B-aligned rows)
  __shared__ float mrow[32];
  float* Hs = (float*)Klds;         // k==1 epilogue overlay: 32 x 128 f32 = 16 KB exact

  if (tid < 32) mrow[tid] = m2g[h*S + qi0 + tid];

  short8 qf[8];
  #pragma unroll
  for (int s = 0; s < 8; ++s)
    qf[s] = *reinterpret_cast<const short8*>(
        qb + (size_t)(qi0 + l31)*E + h*DH + 16*s + 8*half);

  __syncthreads();
  float mreg[16];
  #pragma unroll
  for (int r = 0; r < 16; ++r) mreg[r] = mrow[(r&3) + 8*(r>>2) + 4*half];

  f32x16 acc = {0,0,0,0,0,0,0,0,0,0,0,0,0,0,0,0};

  const int jb    = lane & 15;      // K staging block slot
  const int lrow4 = lane >> 4;
  const int vrow8 = lane >> 3;      // V staging row-in-group
  const int vb7   = lane & 7;
  const int jq    = 32*w + l31;     // QK: j-col (w<2); PV: d-col row in Vlds

  for (int jt = jt_lo; jt < jt_hi; ++jt) {
    const int j0 = jt * 64;
    __syncthreads();                             // prev iter's consumers done
    #pragma unroll
    for (int i = 0; i < 4; ++i) {
      const int ii  = w*4 + i;                   // 0..15
      const int kr  = ii*4 + lrow4;              // K row j-local 0..63
      const int kcc = jb ^ (kr & 15);
      async_copy16(kb + (size_t)(j0 + kr)*E + h*DH + kcc*8, &Klds[ii*512]);
      const int vr  = ii*8 + vrow8;              // V row d 0..127
      const int vcc = vb7 ^ (vr & 7);
      async_copy16(vt + (size_t)(h*DH + vr)*S + j0 + vcc*8, &Vlds[ii*512]);
    }
    float ajv = 0.f;
    if (w < 2) ajv = a2g[h*S + j0 + jq];
    __syncthreads();                             // staged visible

    if (w < 2) {
      // QK^T: this wave's 32 j-cols
      f32x16 qk = {0,0,0,0,0,0,0,0,0,0,0,0,0,0,0,0};
      #pragma unroll
      for (int s = 0; s < 8; ++s) {
        short8 kf = *reinterpret_cast<const short8*>(
            &Klds[jq*128 + ((2*s + half) ^ (jq & 15)) * 8]);
        qk = __builtin_amdgcn_mfma_f32_32x32x16_bf16(qf[s], kf, qk, 0, 0, 0);
      }
      const int jcol = j0 + jq;
      #pragma unroll
      for (int r = 0; r < 16; ++r) {
        const int iloc = (r&3) + 8*(r>>2) + 4*half;
        float pv = (jcol <= qi0 + iloc) ? qk[r] * exp2f(ajv - mreg[r]) : 0.f;
        Psm[iloc*72 + jq] = (short)f2bf(pv);
      }
    }
    __syncthreads();                             // Ps visible

    // P @ V: each wave 32 d-cols, K=64
    #pragma unroll
    for (int s = 0; s < 4; ++s) {
      short8 pf = *reinterpret_cast<const short8*>(&Psm[l31*72 + 16*s + 8*half]);
      short8 vf = *reinterpret_cast<const short8*>(
          &Vlds[jq*64 + ((2*s + half) ^ (jq & 7)) * 8]);
      acc = __builtin_amdgcn_mfma_f32_32x32x16_bf16(pf, vf, acc, 0, 0, 0);
    }
  }

  if (kparts >= 2) {
    // raw O part -> ws; combine kernel finishes (NO device fences here)
    const int pairid = (qt - 16)*8 + h;
    float* dst = opart + ((size_t)pairid*4 + part)*(32*128);
    #pragma unroll
    for (int r = 0; r < 16; ++r) {
      const int iloc = (r&3) + 8*(r>>2) + 4*half;
      dst[iloc*128 + jq] = acc[r];
    }
    return;
  }

  // k==1 epilogue: LN over DH (normalizer is a per-row positive scale -> cancels)
  __syncthreads();
  #pragma unroll
  for (int r = 0; r < 16; ++r)
    Hs[((r&3) + 8*(r>>2) + 4*half)*128 + jq] = acc[r];
  __syncthreads();
  {
    const int row = tid >> 3, seg = tid & 7;
    float vals[16];
    #pragma unroll
    for (int c4 = 0; c4 < 4; ++c4) {
      float4 v4 = *reinterpret_cast<const float4*>(&Hs[row*128 + seg*16 + c4*4]);
      vals[c4*4+0]=v4.x; vals[c4*4+1]=v4.y; vals[c4*4+2]=v4.z; vals[c4*4+3]=v4.w;
    }
    float s1 = 0.f, s2 = 0.f;
    #pragma unroll
    for (int c = 0; c < 16; ++c) { s1 += vals[c]; s2 = fmaf(vals[c], vals[c], s2); }
    #pragma unroll
    for (int off = 1; off < 8; off <<= 1) {
      s1 += __shfl_xor(s1, off);
      s2 += __shfl_xor(s2, off);
    }
    const float mu = s1 * (1.f/128.f);
    float var = fmaxf(s2 * (1.f/128.f) - mu*mu, 0.f);
    const float rs = rsqrtf(var + EPSF);
    const size_t ob = (size_t)(qi0 + row)*E + h*DH + seg*16;
    #pragma unroll
    for (int c = 0; c < 16; ++c)
      out[ob + c] = (vals[c] - mu) * rs * ln[h*DH + seg*16 + c];
  }
}

// ---------------- kernel 4: combine k split parts + LN ----------------
// 384 blocks: one per (h, qt in 16..63); k = 1+qt/16 in {2,3,4}
__global__ __launch_bounds__(256) void combine_kernel(
    const float* __restrict__ opart, const float* __restrict__ ln,
    float* __restrict__ out)
{
  const int t = blockIdx.x;
  const int qt = 16 + (t >> 3);
  const int h  = t & 7;
  const int kparts = 1 + (qt >> 4);
  const float* p0 = opart + (size_t)((qt - 16)*8 + h)*4*(32*128);
  const int tid = threadIdx.x;
  const int row = tid >> 3, seg = tid & 7;
  float vals[16];
  #pragma unroll
  for (int c4 = 0; c4 < 4; ++c4) {
    float4 a = *reinterpret_cast<const float4*>(&p0[row*128 + seg*16 + c4*4]);
    vals[c4*4+0] = a.x; vals[c4*4+1] = a.y;
    vals[c4*4+2] = a.z; vals[c4*4+3] = a.w;
  }
  for (int p = 1; p < kparts; ++p) {
    const float* pp = p0 + (size_t)p*(32*128);
    #pragma unroll
    for (int c4 = 0; c4 < 4; ++c4) {
      float4 a = *reinterpret_cast<const float4*>(&pp[row*128 + seg*16 + c4*4]);
      vals[c4*4+0] += a.x; vals[c4*4+1] += a.y;
      vals[c4*4+2] += a.z; vals[c4*4+3] += a.w;
    }
  }
  float s1 = 0.f, s2 = 0.f;
  #pragma unroll
  for (int c = 0; c < 16; ++c) { s1 += vals[c]; s2 = fmaf(vals[c], vals[c], s2); }
  #pragma unroll
  for (int off = 1; off < 8; off <<= 1) {
    s1 += __shfl_xor(s1, off);
    s2 += __shfl_xor(s2, off);
  }
  const float mu = s1 * (1.f/128.f);
  float var = fmaxf(s2 * (1.f/128.f) - mu*mu, 0.f);
  const float rs = rsqrtf(var + EPSF);
  const size_t ob = (size_t)(qt*32 + row)*E + h*DH + seg*16;
  #pragma unroll
  for (int c = 0; c < 16; ++c)
    out[ob + c] = (vals[c] - mu) * rs * ln[h*DH + seg*16 + c];
}

extern "C" void kernel_launch(void* const* d_in, const int* in_sizes, int n_in,
                              void* d_out, int out_size, void* d_ws, size_t ws_size,
                              hipStream_t stream) {
  const float* q  = (const float*)d_in[0];
  const float* k  = (const float*)d_in[1];
  const float* v  = (const float*)d_in[2];
  const float* Wi = (const float*)d_in[3];
  const float* bi = (const float*)d_in[4];
  const float* Wf = (const float*)d_in[5];
  const float* bf = (const float*)d_in[6];
  const float* ln = (const float*)d_in[7];
  float* out = (float*)d_out;

  // ws: qb 4MB | kb 4MB | vt 4MB | ipre/lsf/a2/m2 4x64KB | opart 25.2MB
  char* base = (char*)d_ws;
  unsigned short* qb  = (unsigned short*)(base);
  unsigned short* kb  = (unsigned short*)(base + (size_t)S*E*2);
  unsigned short* vt  = (unsigned short*)(base + (size_t)S*E*4);
  float* fbase = (float*)(base + (size_t)S*E*6);
  float* ipre  = fbase;
  float* lsf   = fbase + 1*NH*S;
  float* a2    = fbase + 2*NH*S;
  float* m2    = fbase + 3*NH*S;
  float* opart = fbase + 4*NH*S;

  merged_pre_kernel<<<dim3(1152), dim3(256), 0, stream>>>(
      q, k, v, Wi, Wf, bi, bf, qb, kb, vt, ipre, lsf);
  scan_kernel<<<dim3(NH), dim3(256), 0, stream>>>(ipre, lsf, a2, m2);
  attn_kernel<<<dim3(1280), dim3(256), 0, stream>>>(qb, kb, vt, a2, m2, ln, opart, out);
  combine_kernel<<<dim3(384), dim3(256), 0, stream>>>(opart, ln, out);
}

// Round 13
// 128.881 us; speedup vs baseline: 1.0344x; 1.0344x over previous
//
#include <hip/hip_runtime.h>
#include <math.h>

namespace {
constexpr int S  = 2048;
constexpr int E  = 1024;
constexpr int NH = 8;
constexpr int DH = 128;
constexpr float EPSF = 1e-6f;
constexpr float INV_LN2 = 1.4426950408889634f;
}

typedef short short8 __attribute__((ext_vector_type(8)));
typedef float f32x16 __attribute__((ext_vector_type(16)));
typedef float f32x4  __attribute__((ext_vector_type(4)));

__device__ __forceinline__ unsigned short f2bf(float x) {
  unsigned int u = __float_as_uint(x);
  unsigned int r = (u + 0x7fffu + ((u >> 16) & 1u)) >> 16;   // RNE, finite inputs
  return (unsigned short)r;
}

// async 16B/lane global->LDS: LDS dest = wave-uniform base + lane*16
__device__ __forceinline__ void async_copy16(const void* g, void* l) {
  __builtin_amdgcn_global_load_lds(
      (const __attribute__((address_space(1))) unsigned int*)g,
      (__attribute__((address_space(3))) unsigned int*)l, 16, 0, 0);
}

// ---------------- kernel 1 (merged): gates GEMM + V^T + q/k cast ----------------
// b 0..127   : gate GEMM M-tile (16 rows), 4 waves split K=3072 -> ipre/lsf
// b 128..639 : V-transpose 64x64 tiles -> vt bf16
// b 640..1151: q/k cast -> qb/kb bf16
__global__ __launch_bounds__(256) void merged_pre_kernel(
    const float* __restrict__ q, const float* __restrict__ k, const float* __restrict__ v,
    const float* __restrict__ Wi, const float* __restrict__ Wf,
    const float* __restrict__ bi, const float* __restrict__ bfg,
    unsigned short* __restrict__ qb, unsigned short* __restrict__ kb,
    unsigned short* __restrict__ vt,
    float* __restrict__ ipre, float* __restrict__ lsf)
{
  __shared__ __align__(16) char smem[38912];
  const int b = blockIdx.x;
  const int tid = threadIdx.x;

  if (b < 128) {
    const int wv = tid >> 6, lane = tid & 63;
    const int m0 = b * 16;
    const int tr = lane & 15;
    const int ks = (lane >> 4) * 8;
    unsigned short* Wl = (unsigned short*)smem + wv * (16*264);
    float* red = (float*)(smem + 33792);
    f32x4 acc = {0.f, 0.f, 0.f, 0.f};
    const float* srcs[3] = {q, k, v};
    #pragma unroll
    for (int p = 0; p < 3; ++p) {
      // W chunk: Wi/Wf rows (p*E+wv*256 .. +255) x 8 gates are contiguous
      // 2048-float runs -> 8 unrolled float4 loads per source
      const size_t wb = ((size_t)p*E + wv*256) * 8;
      #pragma unroll
      for (int it = 0; it < 8; ++it) {
        const int f = it*64 + lane;
        float4 wi4 = *reinterpret_cast<const float4*>(Wi + wb + (size_t)f*4);
        float4 wf4 = *reinterpret_cast<const float4*>(Wf + wb + (size_t)f*4);
        const int el = f >> 1, n0 = (f & 1) * 4;
        Wl[(n0+0)*264 + el] = f2bf(wi4.x);
        Wl[(n0+1)*264 + el] = f2bf(wi4.y);
        Wl[(n0+2)*264 + el] = f2bf(wi4.z);
        Wl[(n0+3)*264 + el] = f2bf(wi4.w);
        Wl[(n0+8)*264 + el] = f2bf(wf4.x);
        Wl[(n0+9)*264 + el] = f2bf(wf4.y);
        Wl[(n0+10)*264 + el] = f2bf(wf4.z);
        Wl[(n0+11)*264 + el] = f2bf(wf4.w);
      }
      const float* src = srcs[p];
      #pragma unroll
      for (int s = 0; s < 8; ++s) {
        const float* ap = src + (size_t)(m0 + tr)*E + wv*256 + s*32 + ks;
        float4 a0 = *reinterpret_cast<const float4*>(ap);
        float4 a1 = *reinterpret_cast<const float4*>(ap + 4);
        short8 af;
        af[0] = (short)f2bf(a0.x); af[1] = (short)f2bf(a0.y);
        af[2] = (short)f2bf(a0.z); af[3] = (short)f2bf(a0.w);
        af[4] = (short)f2bf(a1.x); af[5] = (short)f2bf(a1.y);
        af[6] = (short)f2bf(a1.z); af[7] = (short)f2bf(a1.w);
        short8 bf8 = *reinterpret_cast<const short8*>(&Wl[tr*264 + s*32 + ks]);
        acc = __builtin_amdgcn_mfma_f32_16x16x32_bf16(af, bf8, acc, 0, 0, 0);
      }
    }
    #pragma unroll
    for (int r = 0; r < 4; ++r)
      red[wv*256 + (lane&15)*16 + (lane>>4)*4 + r] = acc[r];
    __syncthreads();
    {
      const int n = tid & 15, m = tid >> 4;
      float val = red[0*256 + n*16 + m] + red[1*256 + n*16 + m]
                + red[2*256 + n*16 + m] + red[3*256 + n*16 + m];
      const int t = m0 + m;
      if (n < 8) {
        ipre[n*S + t] = val + bi[n];
      } else {
        float fp = val + bfg[n-8];
        lsf[(n-8)*S + t] = fminf(fp, 0.f) - log1pf(__expf(-fabsf(fp)));
      }
    }
  } else if (b < 640) {
    float (*Ts)[65] = (float(*)[65])smem;
    const int bb = b - 128;
    const int j0 = (bb & 31) * 64;
    const int d0 = ((bb >> 5) & 1) * 64;
    const int h  = bb >> 6;
    const int c = tid & 63, r4 = tid >> 6;
    #pragma unroll
    for (int rr = 0; rr < 16; ++rr) {
      int r = r4*16 + rr;
      Ts[r][c] = v[(size_t)(j0 + r)*E + h*DH + d0 + c];
    }
    __syncthreads();
    #pragma unroll
    for (int rr = 0; rr < 16; ++rr) {
      int r = r4*16 + rr;
      vt[(size_t)(h*DH + d0 + r)*S + j0 + c] = f2bf(Ts[c][r]);
    }
  } else {
    const int bb = b - 640;
    constexpr int N4 = S*E/4;
    const float4* src = (bb < 256) ? (const float4*)q : (const float4*)k;
    ushort4* dst = (bb < 256) ? (ushort4*)qb : (ushort4*)kb;
    const int b0 = (bb & 255);
    for (int i = b0*256 + tid; i < N4; i += 256*256) {
      float4 x = src[i];
      ushort4 o;
      o.x = f2bf(x.x); o.y = f2bf(x.y); o.z = f2bf(x.z); o.w = f2bf(x.w);
      dst[i] = o;
    }
  }
}

// ---------------- kernel 2: per-head scans -> a2 = a/ln2, m2 = m/ln2 ----------------
__global__ __launch_bounds__(256) void scan_kernel(
    const float* __restrict__ ipre, const float* __restrict__ lsf,
    float* __restrict__ a2_out, float* __restrict__ m2_out)
{
  const int h = blockIdx.x, tid = threadIdx.x;
  const int lane = tid & 63, wv = tid >> 6;
  constexpr int PER = S / 256;
  const int base = h*S + tid*PER;
  __shared__ float wred[4], wmax[4];

  float c[PER];
  float run = 0.f;
  #pragma unroll
  for (int u = 0; u < PER; u++) { run += lsf[base+u]; c[u] = run; }
  float s = run;
  #pragma unroll
  for (int off = 1; off < 64; off <<= 1) {
    float t = __shfl_up(s, off);
    if (lane >= off) s += t;
  }
  if (lane == 63) wred[wv] = s;
  __syncthreads();
  float wpre = 0.f;
  for (int i = 0; i < wv; i++) wpre += wred[i];
  const float excl = wpre + (s - run);

  float av[PER], mloc[PER];
  float lm = -INFINITY;
  #pragma unroll
  for (int u = 0; u < PER; u++) {
    c[u] += excl;
    av[u] = ipre[base+u] - c[u];
    lm = fmaxf(lm, av[u]);
    mloc[u] = lm;
  }
  float sm_ = lm;
  #pragma unroll
  for (int off = 1; off < 64; off <<= 1) {
    float t = __shfl_up(sm_, off);
    if (lane >= off) sm_ = fmaxf(sm_, t);
  }
  if (lane == 63) wmax[wv] = sm_;
  __syncthreads();
  float wpm = -INFINITY;
  for (int i = 0; i < wv; i++) wpm = fmaxf(wpm, wmax[i]);
  float prev = __shfl_up(sm_, 1);
  if (lane == 0) prev = -INFINITY;
  const float exclm = fmaxf(wpm, prev);
  #pragma unroll
  for (int u = 0; u < PER; u++) {
    float m = fmaxf(exclm, mloc[u]);
    a2_out[base+u] = av[u] * INV_LN2;
    m2_out[base+u] = m * INV_LN2;
  }
}

// ---------------- kernel 3: MFMA causal decay-attention, split-K, LPT order -------
// 768 blocks, h = b&7, idx = b>>3:
//  idx  0..55: split qt 63..36 (both parts)   -- len 8..5
//  idx 56..63: unsplit qt 31..24              -- len 8..7   } first 512 blocks
//  idx 64..71: split qt 35..32                -- len 4..5
//  idx 72..95: unsplit qt 23..0               -- len 6..1
// Split parts write raw O to opart (normalizer cancels; both parts share the
// row basis exp2(a2_j - m2_i)); combine kernel adds + LNs. NO device fences here.
__global__ __launch_bounds__(256, 2) void attn_kernel(
    const unsigned short* __restrict__ qb, const unsigned short* __restrict__ kb,
    const unsigned short* __restrict__ vt,
    const float* __restrict__ a2g, const float* __restrict__ m2g,
    const float* __restrict__ ln, float* __restrict__ opart,
    float* __restrict__ out)
{
  const int h   = blockIdx.x & 7;
  const int idx = blockIdx.x >> 3;
  int qt, part, nspl;
  if (idx < 56)      { qt = 63 - (idx >> 1);        part = idx & 1; nspl = 2; }
  else if (idx < 64) { qt = 31 - (idx - 56);        part = 0;       nspl = 1; }
  else if (idx < 72) { qt = 35 - ((idx - 64) >> 1); part = idx & 1; nspl = 2; }
  else               { qt = 23 - (idx - 72);        part = 0;       nspl = 1; }
  const int N = (qt + 4) >> 2;
  const int jt_lo = part ? (N >> 1) : 0;
  const int jt_hi = (nspl == 2 && part == 0) ? (N >> 1) : N;

  const int tid = threadIdx.x;
  const int w = tid >> 6, lane = tid & 63, l31 = lane & 31, half = lane >> 5;
  const int qi0 = qt * 32;
  const int jcol_off = 32*w + l31;

  __shared__ short Klds[128*128];   // 16B block (row,c): idx = row*16 + (c ^ (row&15))
  __shared__ short Vlds[128*128];
  __shared__ short Psm[32*136];
  __shared__ float mrow[32];
  float* Hs = (float*)Klds;         // epilogue overlay, stride 132 floats

  if (tid < 32) mrow[tid] = m2g[h*S + qi0 + tid];

  short8 qf[8];
  #pragma unroll
  for (int s = 0; s < 8; ++s)
    qf[s] = *reinterpret_cast<const short8*>(
        qb + (size_t)(qi0 + l31)*E + h*DH + 16*s + 8*half);

  __syncthreads();
  float mreg[16];
  #pragma unroll
  for (int r = 0; r < 16; ++r) mreg[r] = mrow[(r&3) + 8*(r>>2) + 4*half];

  f32x16 acc = {0,0,0,0,0,0,0,0,0,0,0,0,0,0,0,0};

  const int lrow4 = lane >> 4;
  const int jb    = lane & 15;
  const int kq_row = 32*w + l31;
  const int kq_swz = kq_row & 15;

  for (int jt = jt_lo; jt < jt_hi; ++jt) {
    const int j0 = jt * 128;
    __syncthreads();                             // prev iter's K/V/Ps consumers done
    #pragma unroll
    for (int i = 0; i < 8; ++i) {
      const int ii  = w*8 + i;
      const int row = ii*4 + lrow4;
      const int cc  = jb ^ (row & 15);
      async_copy16(kb + (size_t)(j0 + row)*E + h*DH + cc*8, &Klds[ii*512]);
      async_copy16(vt + (size_t)(h*DH + row)*S + j0 + cc*8, &Vlds[ii*512]);
    }
    const float ajv = a2g[h*S + j0 + jcol_off];
    __syncthreads();                             // staged visible

    f32x16 qk = {0,0,0,0,0,0,0,0,0,0,0,0,0,0,0,0};
    #pragma unroll
    for (int s = 0; s < 8; ++s) {
      short8 kf = *reinterpret_cast<const short8*>(
          &Klds[kq_row*128 + ((2*s + half) ^ kq_swz) * 8]);
      qk = __builtin_amdgcn_mfma_f32_32x32x16_bf16(qf[s], kf, qk, 0, 0, 0);
    }
    const int jcol = j0 + jcol_off;
    #pragma unroll
    for (int r = 0; r < 16; ++r) {
      const int iloc = (r&3) + 8*(r>>2) + 4*half;
      float pv = (jcol <= qi0 + iloc) ? qk[r] * exp2f(ajv - mreg[r]) : 0.f;
      Psm[iloc*136 + jcol_off] = (short)f2bf(pv);
    }
    __syncthreads();                             // Ps visible
    #pragma unroll
    for (int s = 0; s < 8; ++s) {
      short8 pf = *reinterpret_cast<const short8*>(&Psm[l31*136 + 16*s + 8*half]);
      short8 vf = *reinterpret_cast<const short8*>(
          &Vlds[kq_row*128 + ((2*s + half) ^ kq_swz) * 8]);
      acc = __builtin_amdgcn_mfma_f32_32x32x16_bf16(pf, vf, acc, 0, 0, 0);
    }
  }

  if (nspl == 2) {
    // raw O part -> ws; combine kernel (next dispatch) finishes
    const int pairid = (qt - 32)*8 + h;
    float* dst = opart + ((size_t)pairid*2 + part)*(32*128);
    #pragma unroll
    for (int r = 0; r < 16; ++r) {
      const int iloc = (r&3) + 8*(r>>2) + 4*half;
      dst[iloc*128 + 32*w + l31] = acc[r];
    }
    return;
  }

  // epilogue: LN over DH (normalizer is a per-row positive scale -> cancels)
  __syncthreads();
  #pragma unroll
  for (int r = 0; r < 16; ++r)
    Hs[((r&3) + 8*(r>>2) + 4*half)*132 + 32*w + l31] = acc[r];
  __syncthreads();
  {
    const int row = tid >> 3, seg = tid & 7;
    float vals[16];
    #pragma unroll
    for (int c4 = 0; c4 < 4; ++c4) {
      float4 v4 = *reinterpret_cast<const float4*>(&Hs[row*132 + seg*16 + c4*4]);
      vals[c4*4+0]=v4.x; vals[c4*4+1]=v4.y; vals[c4*4+2]=v4.z; vals[c4*4+3]=v4.w;
    }
    float s1 = 0.f, s2 = 0.f;
    #pragma unroll
    for (int c = 0; c < 16; ++c) { s1 += vals[c]; s2 = fmaf(vals[c], vals[c], s2); }
    #pragma unroll
    for (int off = 1; off < 8; off <<= 1) {
      s1 += __shfl_xor(s1, off);
      s2 += __shfl_xor(s2, off);
    }
    const float mu = s1 * (1.f/128.f);
    float var = fmaxf(s2 * (1.f/128.f) - mu*mu, 0.f);
    const float rs = rsqrtf(var + EPSF);
    const size_t ob = (size_t)(qi0 + row)*E + h*DH + seg*16;
    #pragma unroll
    for (int c = 0; c < 16; ++c)
      out[ob + c] = (vals[c] - mu) * rs * ln[h*DH + seg*16 + c];
  }
}

// ---------------- kernel 4: combine split parts + LN ----------------
// 256 blocks: one per (h, qt>=32) tile
__global__ __launch_bounds__(256) void combine_kernel(
    const float* __restrict__ opart, const float* __restrict__ ln,
    float* __restrict__ out)
{
  const int t = blockIdx.x;
  const int qt = 32 + (t >> 3);
  const int h  = t & 7;
  const float* p0 = opart + (size_t)((qt - 32)*8 + h)*2*(32*128);
  const float* p1 = p0 + 32*128;
  const int tid = threadIdx.x;
  const int row = tid >> 3, seg = tid & 7;
  float vals[16];
  #pragma unroll
  for (int c4 = 0; c4 < 4; ++c4) {
    float4 a = *reinterpret_cast<const float4*>(&p0[row*128 + seg*16 + c4*4]);
    float4 b = *reinterpret_cast<const float4*>(&p1[row*128 + seg*16 + c4*4]);
    vals[c4*4+0] = a.x + b.x; vals[c4*4+1] = a.y + b.y;
    vals[c4*4+2] = a.z + b.z; vals[c4*4+3] = a.w + b.w;
  }
  float s1 = 0.f, s2 = 0.f;
  #pragma unroll
  for (int c = 0; c < 16; ++c) { s1 += vals[c]; s2 = fmaf(vals[c], vals[c], s2); }
  #pragma unroll
  for (int off = 1; off < 8; off <<= 1) {
    s1 += __shfl_xor(s1, off);
    s2 += __shfl_xor(s2, off);
  }
  const float mu = s1 * (1.f/128.f);
  float var = fmaxf(s2 * (1.f/128.f) - mu*mu, 0.f);
  const float rs = rsqrtf(var + EPSF);
  const size_t ob = (size_t)(qt*32 + row)*E + h*DH + seg*16;
  #pragma unroll
  for (int c = 0; c < 16; ++c)
    out[ob + c] = (vals[c] - mu) * rs * ln[h*DH + seg*16 + c];
}

extern "C" void kernel_launch(void* const* d_in, const int* in_sizes, int n_in,
                              void* d_out, int out_size, void* d_ws, size_t ws_size,
                              hipStream_t stream) {
  const float* q  = (const float*)d_in[0];
  const float* k  = (const float*)d_in[1];
  const float* v  = (const float*)d_in[2];
  const float* Wi = (const float*)d_in[3];
  const float* bi = (const float*)d_in[4];
  const float* Wf = (const float*)d_in[5];
  const float* bf = (const float*)d_in[6];
  const float* ln = (const float*)d_in[7];
  float* out = (float*)d_out;

  // ws: qb 4MB | kb 4MB | vt 4MB | ipre/lsf/a2/m2 4x64KB | opart 8MB
  char* base = (char*)d_ws;
  unsigned short* qb  = (unsigned short*)(base);
  unsigned short* kb  = (unsigned short*)(base + (size_t)S*E*2);
  unsigned short* vt  = (unsigned short*)(base + (size_t)S*E*4);
  float* fbase = (float*)(base + (size_t)S*E*6);
  float* ipre  = fbase;
  float* lsf   = fbase + 1*NH*S;
  float* a2    = fbase + 2*NH*S;
  float* m2    = fbase + 3*NH*S;
  float* opart = fbase + 4*NH*S;

  merged_pre_kernel<<<dim3(1152), dim3(256), 0, stream>>>(
      q, k, v, Wi, Wf, bi, bf, qb, kb, vt, ipre, lsf);
  scan_kernel<<<dim3(NH), dim3(256), 0, stream>>>(ipre, lsf, a2, m2);
  attn_kernel<<<dim3(768), dim3(256), 0, stream>>>(qb, kb, vt, a2, m2, ln, opart, out);
  combine_kernel<<<dim3(256), dim3(256), 0, stream>>>(opart, ln, out);
}